// Round 10
// baseline (362.418 us; speedup 1.0000x reference)
//
#include <hip/hip_runtime.h>

// ---------- types ----------
typedef __bf16 bf16x8 __attribute__((ext_vector_type(8)));
typedef float f32x4 __attribute__((ext_vector_type(4)));
typedef float f32x16 __attribute__((ext_vector_type(16)));
typedef unsigned short u16x8 __attribute__((ext_vector_type(8)));
typedef unsigned u32x2 __attribute__((ext_vector_type(2)));
typedef unsigned u32x4 __attribute__((ext_vector_type(4)));

__device__ __forceinline__ unsigned short f2bf(float f) {
  union { float f; unsigned u; } v; v.f = f;
  unsigned r = (v.u + 0x7fffu + ((v.u >> 16) & 1u)) >> 16;
  return (unsigned short)r;
}
__device__ __forceinline__ float bf2f(unsigned short s) {
  union { unsigned u; float f; } v; v.u = ((unsigned)s) << 16;
  return v.f;
}

#define GLD16(g, l)                                                        \
  __builtin_amdgcn_global_load_lds(                                        \
      (const __attribute__((address_space(1))) void*)(g),                  \
      (__attribute__((address_space(3))) void*)(l), 16, 0, 0)

// XOR swizzle for 64-element (128B) rows (flash_attn tiles).
__device__ __forceinline__ int swzc(int row, int colel) {
  return colel ^ ((((row & 7) ^ ((row >> 3) & 7)) & 7) << 3);
}

__device__ __forceinline__ u32x2 plswap(unsigned a, unsigned b) {
  return __builtin_amdgcn_permlane32_swap(a, b, false, false);
}
__device__ __forceinline__ float pair_sum(float x) {
  u32x2 r = plswap(__float_as_uint(x), __float_as_uint(x));
  return __uint_as_float(r.x) + __uint_as_float(r.y);
}
__device__ __forceinline__ unsigned cvtpk(float a, float b) {
  unsigned r;
  asm("v_cvt_pk_bf16_f32 %0, %1, %2" : "=v"(r) : "v"(a), "v"(b));
  return r;
}

// ---------- merged f32 -> bf16 cast: x (2M float4) + 4 weights (1M each) ----------
__global__ __launch_bounds__(256) void cast_all_kernel(
    const float* __restrict__ x,
    const float* __restrict__ w0, const float* __restrict__ w1,
    const float* __restrict__ w2, const float* __restrict__ w3,
    unsigned short* __restrict__ xo,
    unsigned short* __restrict__ o0, unsigned short* __restrict__ o1,
    unsigned short* __restrict__ o2, unsigned short* __restrict__ o3) {
  int i = blockIdx.x * 256 + threadIdx.x;
  int stride = gridDim.x * 256;
  for (; i < 6291456; i += stride) {
    const float* src;
    unsigned short* dst;
    int j;
    if (i < 2097152) {
      src = x; dst = xo; j = i;
    } else {
      int k = i - 2097152;
      int sel = k >> 20;
      src = sel == 0 ? w0 : sel == 1 ? w1 : sel == 2 ? w2 : w3;
      dst = sel == 0 ? o0 : sel == 1 ? o1 : sel == 2 ? o2 : o3;
      j = k & 1048575;
    }
    float4 f = reinterpret_cast<const float4*>(src)[j];
    ushort4 s;
    s.x = f2bf(f.x); s.y = f2bf(f.y); s.z = f2bf(f.z); s.w = f2bf(f.w);
    reinterpret_cast<ushort4*>(dst)[j] = s;
  }
}

// ---------- 4-phase counted-vmcnt NT GEMM ----------
// C_sel[m,c] = sum_k A[m,k]*W_sel[c,k] + b_sel[c].  BM=BN=128, BK=64,
// 256 threads (4 waves, 2Mx2N), 2 blocks/CU (64KB LDS).
// LDS: col-half planes [buf][ks][128][32] (A at 0, B at +16384 elements).
// 4 phases per 2 K-steps; each phase: read 8 frags of one (buf,ks) plane-pair,
// stage one A+B pair (4 GLD16), barrier, 16 MFMA, vmcnt(8), barrier.
// Pair issued at phase p lands by end of p+2, read at p+3.

#define STG_A(STEP, KS, BUF)                                                   \
  GLD16(Ag + (size_t)(row0 + st_row0) * 2048 + (STEP) * 64 + (KS) * 32 +       \
            st_col0,                                                           \
        &ls[((BUF) * 2 + (KS)) * 4096 + (wid * 2) * 512]);                     \
  GLD16(Ag + (size_t)(row0 + st_row1) * 2048 + (STEP) * 64 + (KS) * 32 +       \
            st_col1,                                                           \
        &ls[((BUF) * 2 + (KS)) * 4096 + (wid * 2 + 1) * 512]);

#define STG_B(STEP, KS, BUF)                                                   \
  GLD16(Bg + (size_t)(col0 + st_row0) * 2048 + (STEP) * 64 + (KS) * 32 +       \
            st_col0,                                                           \
        &ls[16384 + ((BUF) * 2 + (KS)) * 4096 + (wid * 2) * 512]);             \
  GLD16(Bg + (size_t)(col0 + st_row1) * 2048 + (STEP) * 64 + (KS) * 32 +       \
            st_col1,                                                           \
        &ls[16384 + ((BUF) * 2 + (KS)) * 4096 + (wid * 2 + 1) * 512]);

#define VM8 asm volatile("s_waitcnt vmcnt(8)" ::: "memory");
#define VM4 asm volatile("s_waitcnt vmcnt(4)" ::: "memory");
#define VM0 asm volatile("s_waitcnt vmcnt(0)" ::: "memory");

#define PHASE4(BUF, KS, STG, VMW)                                              \
  {                                                                            \
    const int pb = ((BUF) * 2 + (KS)) * 4096;                                  \
    bf16x8 af0 = *(const bf16x8*)&ls[pb + offA[0]];                            \
    bf16x8 af1 = *(const bf16x8*)&ls[pb + offA[1]];                            \
    bf16x8 af2 = *(const bf16x8*)&ls[pb + offA[2]];                            \
    bf16x8 af3 = *(const bf16x8*)&ls[pb + offA[3]];                            \
    bf16x8 bf0 = *(const bf16x8*)&ls[16384 + pb + offB[0]];                    \
    bf16x8 bf1 = *(const bf16x8*)&ls[16384 + pb + offB[1]];                    \
    bf16x8 bf2 = *(const bf16x8*)&ls[16384 + pb + offB[2]];                    \
    bf16x8 bf3 = *(const bf16x8*)&ls[16384 + pb + offB[3]];                    \
    STG;                                                                       \
    __builtin_amdgcn_s_barrier();                                              \
    __builtin_amdgcn_s_setprio(1);                                             \
    acc[0][0] = __builtin_amdgcn_mfma_f32_16x16x32_bf16(af0, bf0, acc[0][0], 0, 0, 0); \
    acc[0][1] = __builtin_amdgcn_mfma_f32_16x16x32_bf16(af0, bf1, acc[0][1], 0, 0, 0); \
    acc[0][2] = __builtin_amdgcn_mfma_f32_16x16x32_bf16(af0, bf2, acc[0][2], 0, 0, 0); \
    acc[0][3] = __builtin_amdgcn_mfma_f32_16x16x32_bf16(af0, bf3, acc[0][3], 0, 0, 0); \
    acc[1][0] = __builtin_amdgcn_mfma_f32_16x16x32_bf16(af1, bf0, acc[1][0], 0, 0, 0); \
    acc[1][1] = __builtin_amdgcn_mfma_f32_16x16x32_bf16(af1, bf1, acc[1][1], 0, 0, 0); \
    acc[1][2] = __builtin_amdgcn_mfma_f32_16x16x32_bf16(af1, bf2, acc[1][2], 0, 0, 0); \
    acc[1][3] = __builtin_amdgcn_mfma_f32_16x16x32_bf16(af1, bf3, acc[1][3], 0, 0, 0); \
    acc[2][0] = __builtin_amdgcn_mfma_f32_16x16x32_bf16(af2, bf0, acc[2][0], 0, 0, 0); \
    acc[2][1] = __builtin_amdgcn_mfma_f32_16x16x32_bf16(af2, bf1, acc[2][1], 0, 0, 0); \
    acc[2][2] = __builtin_amdgcn_mfma_f32_16x16x32_bf16(af2, bf2, acc[2][2], 0, 0, 0); \
    acc[2][3] = __builtin_amdgcn_mfma_f32_16x16x32_bf16(af2, bf3, acc[2][3], 0, 0, 0); \
    acc[3][0] = __builtin_amdgcn_mfma_f32_16x16x32_bf16(af3, bf0, acc[3][0], 0, 0, 0); \
    acc[3][1] = __builtin_amdgcn_mfma_f32_16x16x32_bf16(af3, bf1, acc[3][1], 0, 0, 0); \
    acc[3][2] = __builtin_amdgcn_mfma_f32_16x16x32_bf16(af3, bf2, acc[3][2], 0, 0, 0); \
    acc[3][3] = __builtin_amdgcn_mfma_f32_16x16x32_bf16(af3, bf3, acc[3][3], 0, 0, 0); \
    __builtin_amdgcn_s_setprio(0);                                             \
    VMW;                                                                       \
    __builtin_amdgcn_s_barrier();                                              \
  }

template <int F32OUT>
__global__ __launch_bounds__(256, 2) void gemm4p(
    const unsigned short* __restrict__ Ag,
    const unsigned short* __restrict__ W0, const unsigned short* __restrict__ W1,
    const unsigned short* __restrict__ W2,
    const float* __restrict__ b0, const float* __restrict__ b1,
    const float* __restrict__ b2,
    void* __restrict__ C0, void* __restrict__ C1, void* __restrict__ C2) {
  extern __shared__ __align__(16) unsigned short ls[];  // 32768 els = 64KB

  const int lin = blockIdx.y * gridDim.x + blockIdx.x;
  const int cpx = (gridDim.x * gridDim.y) >> 3;
  const int swz = (lin & 7) * cpx + (lin >> 3);
  const int bx = swz % gridDim.x, by = swz / gridDim.x;

  const int gcol = bx * 128;
  const int sel = gcol >> 11;
  const unsigned short* Bg = sel == 0 ? W0 : sel == 1 ? W1 : W2;
  const float* bias = sel == 0 ? b0 : sel == 1 ? b1 : b2;
  void* Cp = sel == 0 ? C0 : sel == 1 ? C1 : C2;
  const int col0 = gcol & 2047;
  const int row0 = by * 128;

  const int tid = threadIdx.x, lane = tid & 63, wid = tid >> 6;
  const int l15 = lane & 15, l4 = lane >> 4;
  const int wm = wid >> 1, wn = wid & 1;

  const int ci0 = wid * 2, ci1 = wid * 2 + 1;
  const int st_row0 = ci0 * 16 + (lane >> 2);
  const int st_row1 = ci1 * 16 + (lane >> 2);
  const int sl2a = ((lane >> 2) & 3) ^ ((lane >> 4) & 3);
  const int st_col0 = (((lane & 3) ^ (sl2a ^ (ci0 & 3))) * 8);
  const int st_col1 = (((lane & 3) ^ (sl2a ^ (ci1 & 3))) * 8);

  const int lsel = (l15 & 3) ^ ((l15 >> 2) & 3);
  int offA[4], offB[4];
#pragma unroll
  for (int f = 0; f < 4; ++f)
    offA[f] = (wm * 64 + f * 16 + l15) * 32 + ((l4 ^ lsel ^ (f & 3)) & 3) * 8;
#pragma unroll
  for (int ni = 0; ni < 4; ++ni)
    offB[ni] =
        (wn * 64 + ni * 16 + l15) * 32 + ((l4 ^ lsel ^ ((wn * 4 + ni) & 3)) & 3) * 8;

  f32x4 acc[4][4] = {};

  // prologue: stage pairs (s0,ks0), (s0,ks1), (s1,ks0); wait oldest; barrier
  STG_A(0, 0, 0); STG_B(0, 0, 0);
  STG_A(0, 1, 0); STG_B(0, 1, 0);
  STG_A(1, 0, 1); STG_B(1, 0, 1);
  VM8;
  __builtin_amdgcn_s_barrier();

  for (int it = 0; it < 15; ++it) {
    const int sE = 2 * it, sO = sE + 1;
    PHASE4(0, 0, STG_A(sO, 1, 1) STG_B(sO, 1, 1), VM8);
    PHASE4(0, 1, STG_A(sE + 2, 0, 0) STG_B(sE + 2, 0, 0), VM8);
    PHASE4(1, 0, STG_A(sE + 2, 1, 0) STG_B(sE + 2, 1, 0), VM8);
    PHASE4(1, 1, STG_A(sO + 2, 0, 1) STG_B(sO + 2, 0, 1), VM8);
  }
  // epilogue iteration (K-steps 30,31): stage only (31,ks1); drain 8->4->0
  PHASE4(0, 0, STG_A(31, 1, 1) STG_B(31, 1, 1), VM8);
  PHASE4(0, 1, , VM4);
  PHASE4(1, 0, , VM0);
  PHASE4(1, 1, , );

  // C-write
#pragma unroll
  for (int f = 0; f < 4; ++f)
#pragma unroll
    for (int ni = 0; ni < 4; ++ni)
#pragma unroll
      for (int r = 0; r < 4; ++r) {
        int row = row0 + wm * 64 + f * 16 + l4 * 4 + r;
        int col = col0 + wn * 64 + ni * 16 + l15;
        float v = acc[f][ni][r] + bias[col];
        if (F32OUT)
          ((float*)Cp)[(size_t)row * 2048 + col] = v;
        else
          ((unsigned short*)Cp)[(size_t)row * 2048 + col] = f2bf(v);
      }
}

// ---------- combined in-place RMS norm: Q rows then K rows ----------
__global__ __launch_bounds__(256) void rmsnorm2_kernel(
    unsigned short* __restrict__ Qb, unsigned short* __restrict__ Kb,
    const float* __restrict__ qw, const float* __restrict__ kw) {
  const int row = blockIdx.x;
  unsigned short* p;
  const float* w;
  if (row < 4096) { p = Qb + (size_t)row * 2048; w = qw; }
  else            { p = Kb + (size_t)(row - 4096) * 2048; w = kw; }
  const int tid = threadIdx.x;
  u16x8 v = *(const u16x8*)&p[tid * 8];
  float f[8];
  float ss = 0.f;
#pragma unroll
  for (int j = 0; j < 8; ++j) { f[j] = bf2f(v[j]); ss += f[j] * f[j]; }
#pragma unroll
  for (int m = 1; m < 64; m <<= 1) ss += __shfl_xor(ss, m, 64);
  __shared__ float red[4];
  const int wid = tid >> 6, lane = tid & 63;
  if (lane == 0) red[wid] = ss;
  __syncthreads();
  float tot = red[0] + red[1] + red[2] + red[3];
  float rs = rsqrtf(tot * (1.0f / 2048.0f) + 1e-6f);
  u16x8 o;
#pragma unroll
  for (int j = 0; j < 8; ++j) o[j] = f2bf(f[j] * rs * w[tid * 8 + j]);
  *(u16x8*)&p[tid * 8] = o;
}

// ---------- flash attention: fat waves (64 q/wave), swapped 32x32 ----------
// (unchanged from round 9)
__global__ __launch_bounds__(256, 2) void flash_attn(
    const unsigned short* __restrict__ Q, const unsigned short* __restrict__ K,
    const unsigned short* __restrict__ V, unsigned short* __restrict__ O) {
  __shared__ unsigned short Ks[2][64 * 64];   // [key][dh], swizzled
  __shared__ unsigned short Vs[2][64 * 64];   // transposed [dh][key], swizzled
  const int bid = blockIdx.x;
  const int sw = (bid & 7) * 64 + (bid >> 3);    // XCD-chunked (512 % 8 == 0)
  const int h = sw >> 4;
  const int q0 = (sw & 15) * 256;
  const int tid = threadIdx.x, lane = tid & 63, wid = tid >> 6;
  const int l31 = lane & 31, hi = lane >> 5;

  const int kr0 = wid * 16 + (lane >> 3);
  const int kc0 = (lane & 7) * 8;
  const int vkey = (tid & 31) * 2;
  const int vd0 = (tid >> 5) * 8;

  const float QSCALE = 0.125f * 1.44269504f;
  bf16x8 qf0[4], qf1[4];
  {
    const int qr0 = q0 + wid * 64 + l31;
#pragma unroll
    for (int kt = 0; kt < 4; ++kt) {
      bf16x8 r0 = *(const bf16x8*)&Q[(size_t)qr0 * 2048 + h * 64 + kt * 16 + hi * 8];
      bf16x8 r1 = *(const bf16x8*)&Q[(size_t)(qr0 + 32) * 2048 + h * 64 + kt * 16 + hi * 8];
#pragma unroll
      for (int j = 0; j < 8; ++j) {
        qf0[kt][j] = (__bf16)((float)r0[j] * QSCALE);
        qf1[kt][j] = (__bf16)((float)r1[j] * QSCALE);
      }
    }
  }

  int off[2][4];
#pragma unroll
  for (int kb = 0; kb < 2; ++kb) {
    const int row = kb * 32 + l31;
    const int sl = (((row & 7) ^ ((row >> 3) & 7)) & 7) << 3;
#pragma unroll
    for (int kt = 0; kt < 4; ++kt)
      off[kb][kt] = row * 64 + ((kt * 16 + hi * 8) ^ sl);
  }

  float l0 = 0.f, l1 = 0.f;
  f32x16 oa0[2] = {}, oa1[2] = {};

  u16x8 kreg0, kreg1, vreg0, vreg1;
  auto loadKV = [&](int kt0) {
    kreg0 = *(const u16x8*)&K[(size_t)(kt0 + kr0) * 2048 + h * 64 + kc0];
    kreg1 = *(const u16x8*)&K[(size_t)(kt0 + kr0 + 8) * 2048 + h * 64 + kc0];
    vreg0 = *(const u16x8*)&V[(size_t)(kt0 + vkey) * 2048 + h * 64 + vd0];
    vreg1 = *(const u16x8*)&V[(size_t)(kt0 + vkey + 1) * 2048 + h * 64 + vd0];
  };
  auto writeKV = [&](int b) {
    *(u16x8*)&Ks[b][kr0 * 64 + swzc(kr0, kc0)] = kreg0;
    *(u16x8*)&Ks[b][(kr0 + 8) * 64 + swzc(kr0 + 8, kc0)] = kreg1;
#pragma unroll
    for (int d = 0; d < 8; ++d) {
      int row = vd0 + d;
      *(unsigned*)&Vs[b][row * 64 + swzc(row, vkey)] =
          (unsigned)vreg0[d] | ((unsigned)vreg1[d] << 16);
    }
  };

  loadKV(0);
  writeKV(0);
  __syncthreads();

  for (int t = 0; t < 64; ++t) {
    const int cur = t & 1;
    if (t < 63) loadKV((t + 1) * 64);

    const unsigned short* Kc = Ks[cur];
    const unsigned short* Vc = Vs[cur];

    bf16x8 kf[2][4];
#pragma unroll
    for (int kb = 0; kb < 2; ++kb)
#pragma unroll
      for (int kt = 0; kt < 4; ++kt)
        kf[kb][kt] = *(const bf16x8*)&Kc[off[kb][kt]];

    f32x16 st0[2], st1[2];
    __builtin_amdgcn_s_setprio(1);
#pragma unroll
    for (int kb = 0; kb < 2; ++kb) {
      f32x16 a = {};
#pragma unroll
      for (int kt = 0; kt < 4; ++kt)
        a = __builtin_amdgcn_mfma_f32_32x32x16_bf16(kf[kb][kt], qf0[kt], a, 0, 0, 0);
      st0[kb] = a;
    }
#pragma unroll
    for (int kb = 0; kb < 2; ++kb) {
      f32x16 a = {};
#pragma unroll
      for (int kt = 0; kt < 4; ++kt)
        a = __builtin_amdgcn_mfma_f32_32x32x16_bf16(kf[kb][kt], qf1[kt], a, 0, 0, 0);
      st1[kb] = a;
    }
    __builtin_amdgcn_s_setprio(0);

    unsigned pk0[16], pk1[16];
    {
      float s0 = 0.f, s1 = 0.f, s2 = 0.f, s3 = 0.f;
#pragma unroll
      for (int kb = 0; kb < 2; ++kb)
#pragma unroll
        for (int j = 0; j < 8; ++j) {
          float pa = __builtin_amdgcn_exp2f(st0[kb][2 * j]);
          float pb = __builtin_amdgcn_exp2f(st0[kb][2 * j + 1]);
          if ((j & 3) == 0) s0 += pa + pb;
          else if ((j & 3) == 1) s1 += pa + pb;
          else if ((j & 3) == 2) s2 += pa + pb;
          else s3 += pa + pb;
          pk0[kb * 8 + j] = cvtpk(pa, pb);
        }
      l0 += (s0 + s1) + (s2 + s3);
    }
    {
      float s0 = 0.f, s1 = 0.f, s2 = 0.f, s3 = 0.f;
#pragma unroll
      for (int kb = 0; kb < 2; ++kb)
#pragma unroll
        for (int j = 0; j < 8; ++j) {
          float pa = __builtin_amdgcn_exp2f(st1[kb][2 * j]);
          float pb = __builtin_amdgcn_exp2f(st1[kb][2 * j + 1]);
          if ((j & 3) == 0) s0 += pa + pb;
          else if ((j & 3) == 1) s1 += pa + pb;
          else if ((j & 3) == 2) s2 += pa + pb;
          else s3 += pa + pb;
          pk1[kb * 8 + j] = cvtpk(pa, pb);
        }
      l1 += (s0 + s1) + (s2 + s3);
    }

    bf16x8 pfrag0[4], pfrag1[4];
#pragma unroll
    for (int kt = 0; kt < 4; ++kt) {
      u32x2 sa = plswap(pk0[4 * kt + 0], pk0[4 * kt + 2]);
      u32x2 sb = plswap(pk0[4 * kt + 1], pk0[4 * kt + 3]);
      union { u32x4 u; bf16x8 b; } w;
      w.u.x = sa.x; w.u.y = sb.x; w.u.z = sa.y; w.u.w = sb.y;
      pfrag0[kt] = w.b;
      u32x2 sc = plswap(pk1[4 * kt + 0], pk1[4 * kt + 2]);
      u32x2 sd = plswap(pk1[4 * kt + 1], pk1[4 * kt + 3]);
      union { u32x4 u; bf16x8 b; } w2;
      w2.u.x = sc.x; w2.u.y = sd.x; w2.u.z = sc.y; w2.u.w = sd.y;
      pfrag1[kt] = w2.b;
    }

    __builtin_amdgcn_s_setprio(1);
#pragma unroll
    for (int dv = 0; dv < 2; ++dv) {
      bf16x8 vf[4];
#pragma unroll
      for (int kt = 0; kt < 4; ++kt)
        vf[kt] = *(const bf16x8*)&Vc[off[dv][kt]];
#pragma unroll
      for (int kt = 0; kt < 4; ++kt)
        oa0[dv] = __builtin_amdgcn_mfma_f32_32x32x16_bf16(vf[kt], pfrag0[kt], oa0[dv], 0, 0, 0);
#pragma unroll
      for (int kt = 0; kt < 4; ++kt)
        oa1[dv] = __builtin_amdgcn_mfma_f32_32x32x16_bf16(vf[kt], pfrag1[kt], oa1[dv], 0, 0, 0);
    }
    __builtin_amdgcn_s_setprio(0);

    if (t < 63) {
      writeKV(cur ^ 1);
      __syncthreads();
    }
  }

  const float inv0 = 1.0f / pair_sum(l0);
  const float inv1 = 1.0f / pair_sum(l1);
  const int qr0 = q0 + wid * 64 + l31;
#pragma unroll
  for (int dv = 0; dv < 2; ++dv)
#pragma unroll
    for (int tq = 0; tq < 4; ++tq) {
      int dh = 32 * dv + 8 * tq + 4 * hi;
      unsigned a0 = cvtpk(oa0[dv][4 * tq + 0] * inv0, oa0[dv][4 * tq + 1] * inv0);
      unsigned a1 = cvtpk(oa0[dv][4 * tq + 2] * inv0, oa0[dv][4 * tq + 3] * inv0);
      u32x2 wa = {a0, a1};
      *(u32x2*)&O[(size_t)qr0 * 2048 + h * 64 + dh] = wa;
      unsigned b0 = cvtpk(oa1[dv][4 * tq + 0] * inv1, oa1[dv][4 * tq + 1] * inv1);
      unsigned b1 = cvtpk(oa1[dv][4 * tq + 2] * inv1, oa1[dv][4 * tq + 3] * inv1);
      u32x2 wb = {b0, b1};
      *(u32x2*)&O[(size_t)(qr0 + 32) * 2048 + h * 64 + dh] = wb;
    }
}

// ---------- launch ----------
extern "C" void kernel_launch(void* const* d_in, const int* in_sizes, int n_in,
                              void* d_out, int out_size, void* d_ws, size_t ws_size,
                              hipStream_t stream) {
  const float* x  = (const float*)d_in[0];
  const float* Wq = (const float*)d_in[1];
  const float* bq = (const float*)d_in[2];
  const float* Wk = (const float*)d_in[3];
  const float* bk = (const float*)d_in[4];
  const float* Wv = (const float*)d_in[5];
  const float* bv = (const float*)d_in[6];
  const float* qn = (const float*)d_in[7];
  const float* kn = (const float*)d_in[8];
  const float* Wo = (const float*)d_in[9];
  const float* bo = (const float*)d_in[10];

  char* w = (char*)d_ws;
  unsigned short* Xbf = (unsigned short*)(w);                 // reused for O
  unsigned short* Wqb = (unsigned short*)(w + 16777216);
  unsigned short* Wkb = (unsigned short*)(w + 25165824);
  unsigned short* Wvb = (unsigned short*)(w + 33554432);
  unsigned short* Wob = (unsigned short*)(w + 41943040);
  unsigned short* Qb  = (unsigned short*)(w + 50331648);
  unsigned short* Kb  = (unsigned short*)(w + 67108864);
  unsigned short* Vb  = (unsigned short*)(w + 83886080);
  unsigned short* Ob  = Xbf;

  cast_all_kernel<<<3072, 256, 0, stream>>>(x, Wq, Wk, Wv, Wo,
                                            Xbf, Wqb, Wkb, Wvb, Wob);

  gemm4p<0><<<dim3(48, 32), 256, 65536, stream>>>(
      Xbf, Wqb, Wkb, Wvb, bq, bk, bv, Qb, Kb, Vb);

  rmsnorm2_kernel<<<8192, 256, 0, stream>>>(Qb, Kb, qn, kn);

  flash_attn<<<512, 256, 0, stream>>>(Qb, Kb, Vb, Ob);

  gemm4p<1><<<dim3(16, 32), 256, 65536, stream>>>(
      Ob, Wob, Wob, Wob, bo, bo, bo, d_out, d_out, d_out);
}

// Round 11
// 357.791 us; speedup vs baseline: 1.0129x; 1.0129x over previous
//
#include <hip/hip_runtime.h>

// ---------- types ----------
typedef __bf16 bf16x8 __attribute__((ext_vector_type(8)));
typedef float f32x4 __attribute__((ext_vector_type(4)));
typedef float f32x16 __attribute__((ext_vector_type(16)));
typedef unsigned short u16x8 __attribute__((ext_vector_type(8)));
typedef unsigned u32x2 __attribute__((ext_vector_type(2)));
typedef unsigned u32x4 __attribute__((ext_vector_type(4)));

__device__ __forceinline__ unsigned short f2bf(float f) {
  union { float f; unsigned u; } v; v.f = f;
  unsigned r = (v.u + 0x7fffu + ((v.u >> 16) & 1u)) >> 16;
  return (unsigned short)r;
}
__device__ __forceinline__ float bf2f(unsigned short s) {
  union { unsigned u; float f; } v; v.u = ((unsigned)s) << 16;
  return v.f;
}

#define GLD16(g, l)                                                        \
  __builtin_amdgcn_global_load_lds(                                        \
      (const __attribute__((address_space(1))) void*)(g),                  \
      (__attribute__((address_space(3))) void*)(l), 16, 0, 0)

// XOR swizzle for 64-element (128B) rows (flash_attn tiles).
__device__ __forceinline__ int swzc(int row, int colel) {
  return colel ^ ((((row & 7) ^ ((row >> 3) & 7)) & 7) << 3);
}

__device__ __forceinline__ u32x2 plswap(unsigned a, unsigned b) {
  return __builtin_amdgcn_permlane32_swap(a, b, false, false);
}
__device__ __forceinline__ float pair_sum(float x) {
  u32x2 r = plswap(__float_as_uint(x), __float_as_uint(x));
  return __uint_as_float(r.x) + __uint_as_float(r.y);
}
__device__ __forceinline__ unsigned cvtpk(float a, float b) {
  unsigned r;
  asm("v_cvt_pk_bf16_f32 %0, %1, %2" : "=v"(r) : "v"(a), "v"(b));
  return r;
}

// ---------- merged f32 -> bf16 cast: x (2M float4) + 4 weights (1M each) ----------
__global__ __launch_bounds__(256) void cast_all_kernel(
    const float* __restrict__ x,
    const float* __restrict__ w0, const float* __restrict__ w1,
    const float* __restrict__ w2, const float* __restrict__ w3,
    unsigned short* __restrict__ xo,
    unsigned short* __restrict__ o0, unsigned short* __restrict__ o1,
    unsigned short* __restrict__ o2, unsigned short* __restrict__ o3) {
  int i = blockIdx.x * 256 + threadIdx.x;
  int stride = gridDim.x * 256;
  for (; i < 6291456; i += stride) {
    const float* src;
    unsigned short* dst;
    int j;
    if (i < 2097152) {
      src = x; dst = xo; j = i;
    } else {
      int k = i - 2097152;
      int sel = k >> 20;
      src = sel == 0 ? w0 : sel == 1 ? w1 : sel == 2 ? w2 : w3;
      dst = sel == 0 ? o0 : sel == 1 ? o1 : sel == 2 ? o2 : o3;
      j = k & 1048575;
    }
    float4 f = reinterpret_cast<const float4*>(src)[j];
    ushort4 s;
    s.x = f2bf(f.x); s.y = f2bf(f.y); s.z = f2bf(f.z); s.w = f2bf(f.w);
    reinterpret_cast<ushort4*>(dst)[j] = s;
  }
}

// ---------- 256x128-tile counted-vmcnt NT GEMM (m201-family schedule) ----------
// C_sel[m,c] = sum_k A[m,k]*W_sel[c,k] + b_sel[c].  BM=256, BN=128,
// 512 threads (8 waves, 4Mx2N, 64x64 out/wave), 96KB static LDS, 1 block/CU.
// K split into 64 slices of 32; 4 cyclic LDS slots; per phase:
// 8 ds_read_b128 + stage slice p+3 (3 GLD16) + barrier + 16 MFMA + vmcnt(6)
// + barrier. Slice staged at p lands before its read at p+3 (vmcnt keeps at
// most 2 newer slices in flight); slot overwrites are 2 barriers after the
// last read of the old slice.

#define SGA(SLICE, SLOT)                                                       \
  GLD16(Ag + (size_t)(row0 + ar0) * 2048 + (SLICE) * 32 + ac0,                 \
        &As[SLOT][ci0 * 512]);                                                 \
  GLD16(Ag + (size_t)(row0 + ar1) * 2048 + (SLICE) * 32 + ac1,                 \
        &As[SLOT][ci1 * 512]);

#define SGB(SLICE, SLOT)                                                       \
  GLD16(Bg + (size_t)(col0 + br0) * 2048 + (SLICE) * 32 + bc0,                 \
        &Bs[SLOT][wid * 512]);

#define VM6 asm volatile("s_waitcnt vmcnt(6)" ::: "memory");
#define VM3 asm volatile("s_waitcnt vmcnt(3)" ::: "memory");
#define VM0 asm volatile("s_waitcnt vmcnt(0)" ::: "memory");

#define PH256(SLOT, STG, VMW)                                                  \
  {                                                                            \
    bf16x8 a0 = *(const bf16x8*)&As[SLOT][offA[0]];                            \
    bf16x8 a1 = *(const bf16x8*)&As[SLOT][offA[1]];                            \
    bf16x8 a2 = *(const bf16x8*)&As[SLOT][offA[2]];                            \
    bf16x8 a3 = *(const bf16x8*)&As[SLOT][offA[3]];                            \
    bf16x8 b0 = *(const bf16x8*)&Bs[SLOT][offB[0]];                            \
    bf16x8 b1 = *(const bf16x8*)&Bs[SLOT][offB[1]];                            \
    bf16x8 b2 = *(const bf16x8*)&Bs[SLOT][offB[2]];                            \
    bf16x8 b3 = *(const bf16x8*)&Bs[SLOT][offB[3]];                            \
    STG;                                                                       \
    __builtin_amdgcn_s_barrier();                                              \
    __builtin_amdgcn_s_setprio(1);                                             \
    acc[0][0] = __builtin_amdgcn_mfma_f32_16x16x32_bf16(a0, b0, acc[0][0], 0, 0, 0); \
    acc[0][1] = __builtin_amdgcn_mfma_f32_16x16x32_bf16(a0, b1, acc[0][1], 0, 0, 0); \
    acc[0][2] = __builtin_amdgcn_mfma_f32_16x16x32_bf16(a0, b2, acc[0][2], 0, 0, 0); \
    acc[0][3] = __builtin_amdgcn_mfma_f32_16x16x32_bf16(a0, b3, acc[0][3], 0, 0, 0); \
    acc[1][0] = __builtin_amdgcn_mfma_f32_16x16x32_bf16(a1, b0, acc[1][0], 0, 0, 0); \
    acc[1][1] = __builtin_amdgcn_mfma_f32_16x16x32_bf16(a1, b1, acc[1][1], 0, 0, 0); \
    acc[1][2] = __builtin_amdgcn_mfma_f32_16x16x32_bf16(a1, b2, acc[1][2], 0, 0, 0); \
    acc[1][3] = __builtin_amdgcn_mfma_f32_16x16x32_bf16(a1, b3, acc[1][3], 0, 0, 0); \
    acc[2][0] = __builtin_amdgcn_mfma_f32_16x16x32_bf16(a2, b0, acc[2][0], 0, 0, 0); \
    acc[2][1] = __builtin_amdgcn_mfma_f32_16x16x32_bf16(a2, b1, acc[2][1], 0, 0, 0); \
    acc[2][2] = __builtin_amdgcn_mfma_f32_16x16x32_bf16(a2, b2, acc[2][2], 0, 0, 0); \
    acc[2][3] = __builtin_amdgcn_mfma_f32_16x16x32_bf16(a2, b3, acc[2][3], 0, 0, 0); \
    acc[3][0] = __builtin_amdgcn_mfma_f32_16x16x32_bf16(a3, b0, acc[3][0], 0, 0, 0); \
    acc[3][1] = __builtin_amdgcn_mfma_f32_16x16x32_bf16(a3, b1, acc[3][1], 0, 0, 0); \
    acc[3][2] = __builtin_amdgcn_mfma_f32_16x16x32_bf16(a3, b2, acc[3][2], 0, 0, 0); \
    acc[3][3] = __builtin_amdgcn_mfma_f32_16x16x32_bf16(a3, b3, acc[3][3], 0, 0, 0); \
    __builtin_amdgcn_s_setprio(0);                                             \
    VMW;                                                                       \
    __builtin_amdgcn_s_barrier();                                              \
  }

template <int F32OUT>
__global__ __launch_bounds__(512, 2) void gemm256(
    const unsigned short* __restrict__ Ag,
    const unsigned short* __restrict__ W0, const unsigned short* __restrict__ W1,
    const unsigned short* __restrict__ W2,
    const float* __restrict__ b0, const float* __restrict__ b1,
    const float* __restrict__ b2,
    void* __restrict__ C0, void* __restrict__ C1, void* __restrict__ C2) {
  __shared__ unsigned short As[4][8192];  // 64 KB: 4 slots of [256][32]
  __shared__ unsigned short Bs[4][4096];  // 32 KB: 4 slots of [128][32]

  // XCD-bijective swizzle (grid total divisible by 8)
  const int lin = blockIdx.y * gridDim.x + blockIdx.x;
  const int cpx = (gridDim.x * gridDim.y) >> 3;
  const int swz = (lin & 7) * cpx + (lin >> 3);
  const int bx = swz % gridDim.x, by = swz / gridDim.x;

  const int gcol = bx * 128;
  const int sel = gcol >> 11;
  const unsigned short* Bg = sel == 0 ? W0 : sel == 1 ? W1 : W2;
  const float* bias = sel == 0 ? b0 : sel == 1 ? b1 : b2;
  void* Cp = sel == 0 ? C0 : sel == 1 ? C1 : C2;
  const int col0 = gcol & 2047;
  const int row0 = by * 256;

  const int tid = threadIdx.x, lane = tid & 63, wid = tid >> 6;  // 8 waves
  const int l15 = lane & 15, l4 = lane >> 4;
  const int wm = wid >> 1, wn = wid & 1;

  // staging geometry (16-row chunks of 32 els; XOR-preswizzled source col)
  const int sl2a = ((lane >> 2) & 3) ^ ((lane >> 4) & 3);
  const int ci0 = wid * 2, ci1 = wid * 2 + 1;
  const int ar0 = ci0 * 16 + (lane >> 2);
  const int ar1 = ci1 * 16 + (lane >> 2);
  const int ac0 = (((lane & 3) ^ sl2a ^ (ci0 & 3)) & 3) * 8;
  const int ac1 = (((lane & 3) ^ sl2a ^ (ci1 & 3)) & 3) * 8;
  const int br0 = wid * 16 + (lane >> 2);
  const int bc0 = (((lane & 3) ^ sl2a ^ (wid & 3)) & 3) * 8;

  // fragment read offsets (elements within a slot)
  const int lsel = (l15 & 3) ^ ((l15 >> 2) & 3);
  int offA[4], offB[4];
#pragma unroll
  for (int f = 0; f < 4; ++f)
    offA[f] = (wm * 64 + f * 16 + l15) * 32 + ((l4 ^ lsel ^ f) & 3) * 8;
#pragma unroll
  for (int ni = 0; ni < 4; ++ni)
    offB[ni] = (wn * 64 + ni * 16 + l15) * 32 + ((l4 ^ lsel ^ ni) & 3) * 8;

  f32x4 acc[4][4] = {};

  // prologue: stage slices 0,1,2 (9 loads); wait for slice 0; barrier
  SGA(0, 0); SGB(0, 0);
  SGA(1, 1); SGB(1, 1);
  SGA(2, 2); SGB(2, 2);
  VM6;
  __builtin_amdgcn_s_barrier();

  for (int it = 0; it < 15; ++it) {
    const int s = 4 * it;
    PH256(0, SGA(s + 3, 3) SGB(s + 3, 3), VM6);
    PH256(1, SGA(s + 4, 0) SGB(s + 4, 0), VM6);
    PH256(2, SGA(s + 5, 1) SGB(s + 5, 1), VM6);
    PH256(3, SGA(s + 6, 2) SGB(s + 6, 2), VM6);
  }
  // tail: phases 60..63 (slices 60..63); stage last slice 63; drain 6->3->0
  PH256(0, SGA(63, 3) SGB(63, 3), VM6);
  PH256(1, , VM3);
  PH256(2, , VM0);
  PH256(3, , );

  // C-write
#pragma unroll
  for (int f = 0; f < 4; ++f)
#pragma unroll
    for (int ni = 0; ni < 4; ++ni)
#pragma unroll
      for (int r = 0; r < 4; ++r) {
        int row = row0 + wm * 64 + f * 16 + l4 * 4 + r;
        int col = col0 + wn * 64 + ni * 16 + l15;
        float v = acc[f][ni][r] + bias[col];
        if (F32OUT)
          ((float*)Cp)[(size_t)row * 2048 + col] = v;
        else
          ((unsigned short*)Cp)[(size_t)row * 2048 + col] = f2bf(v);
      }
}

// ---------- combined in-place RMS norm: Q rows then K rows ----------
__global__ __launch_bounds__(256) void rmsnorm2_kernel(
    unsigned short* __restrict__ Qb, unsigned short* __restrict__ Kb,
    const float* __restrict__ qw, const float* __restrict__ kw) {
  const int row = blockIdx.x;
  unsigned short* p;
  const float* w;
  if (row < 4096) { p = Qb + (size_t)row * 2048; w = qw; }
  else            { p = Kb + (size_t)(row - 4096) * 2048; w = kw; }
  const int tid = threadIdx.x;
  u16x8 v = *(const u16x8*)&p[tid * 8];
  float f[8];
  float ss = 0.f;
#pragma unroll
  for (int j = 0; j < 8; ++j) { f[j] = bf2f(v[j]); ss += f[j] * f[j]; }
#pragma unroll
  for (int m = 1; m < 64; m <<= 1) ss += __shfl_xor(ss, m, 64);
  __shared__ float red[4];
  const int wid = tid >> 6, lane = tid & 63;
  if (lane == 0) red[wid] = ss;
  __syncthreads();
  float tot = red[0] + red[1] + red[2] + red[3];
  float rs = rsqrtf(tot * (1.0f / 2048.0f) + 1e-6f);
  u16x8 o;
#pragma unroll
  for (int j = 0; j < 8; ++j) o[j] = f2bf(f[j] * rs * w[tid * 8 + j]);
  *(u16x8*)&p[tid * 8] = o;
}

// ---------- flash attention: fat waves (64 q/wave), swapped 32x32 ----------
// (unchanged from round 9)
__global__ __launch_bounds__(256, 2) void flash_attn(
    const unsigned short* __restrict__ Q, const unsigned short* __restrict__ K,
    const unsigned short* __restrict__ V, unsigned short* __restrict__ O) {
  __shared__ unsigned short Ks[2][64 * 64];   // [key][dh], swizzled
  __shared__ unsigned short Vs[2][64 * 64];   // transposed [dh][key], swizzled
  const int bid = blockIdx.x;
  const int sw = (bid & 7) * 64 + (bid >> 3);    // XCD-chunked (512 % 8 == 0)
  const int h = sw >> 4;
  const int q0 = (sw & 15) * 256;
  const int tid = threadIdx.x, lane = tid & 63, wid = tid >> 6;
  const int l31 = lane & 31, hi = lane >> 5;

  const int kr0 = wid * 16 + (lane >> 3);
  const int kc0 = (lane & 7) * 8;
  const int vkey = (tid & 31) * 2;
  const int vd0 = (tid >> 5) * 8;

  const float QSCALE = 0.125f * 1.44269504f;
  bf16x8 qf0[4], qf1[4];
  {
    const int qr0 = q0 + wid * 64 + l31;
#pragma unroll
    for (int kt = 0; kt < 4; ++kt) {
      bf16x8 r0 = *(const bf16x8*)&Q[(size_t)qr0 * 2048 + h * 64 + kt * 16 + hi * 8];
      bf16x8 r1 = *(const bf16x8*)&Q[(size_t)(qr0 + 32) * 2048 + h * 64 + kt * 16 + hi * 8];
#pragma unroll
      for (int j = 0; j < 8; ++j) {
        qf0[kt][j] = (__bf16)((float)r0[j] * QSCALE);
        qf1[kt][j] = (__bf16)((float)r1[j] * QSCALE);
      }
    }
  }

  int off[2][4];
#pragma unroll
  for (int kb = 0; kb < 2; ++kb) {
    const int row = kb * 32 + l31;
    const int sl = (((row & 7) ^ ((row >> 3) & 7)) & 7) << 3;
#pragma unroll
    for (int kt = 0; kt < 4; ++kt)
      off[kb][kt] = row * 64 + ((kt * 16 + hi * 8) ^ sl);
  }

  float l0 = 0.f, l1 = 0.f;
  f32x16 oa0[2] = {}, oa1[2] = {};

  u16x8 kreg0, kreg1, vreg0, vreg1;
  auto loadKV = [&](int kt0) {
    kreg0 = *(const u16x8*)&K[(size_t)(kt0 + kr0) * 2048 + h * 64 + kc0];
    kreg1 = *(const u16x8*)&K[(size_t)(kt0 + kr0 + 8) * 2048 + h * 64 + kc0];
    vreg0 = *(const u16x8*)&V[(size_t)(kt0 + vkey) * 2048 + h * 64 + vd0];
    vreg1 = *(const u16x8*)&V[(size_t)(kt0 + vkey + 1) * 2048 + h * 64 + vd0];
  };
  auto writeKV = [&](int b) {
    *(u16x8*)&Ks[b][kr0 * 64 + swzc(kr0, kc0)] = kreg0;
    *(u16x8*)&Ks[b][(kr0 + 8) * 64 + swzc(kr0 + 8, kc0)] = kreg1;
#pragma unroll
    for (int d = 0; d < 8; ++d) {
      int row = vd0 + d;
      *(unsigned*)&Vs[b][row * 64 + swzc(row, vkey)] =
          (unsigned)vreg0[d] | ((unsigned)vreg1[d] << 16);
    }
  };

  loadKV(0);
  writeKV(0);
  __syncthreads();

  for (int t = 0; t < 64; ++t) {
    const int cur = t & 1;
    if (t < 63) loadKV((t + 1) * 64);

    const unsigned short* Kc = Ks[cur];
    const unsigned short* Vc = Vs[cur];

    bf16x8 kf[2][4];
#pragma unroll
    for (int kb = 0; kb < 2; ++kb)
#pragma unroll
      for (int kt = 0; kt < 4; ++kt)
        kf[kb][kt] = *(const bf16x8*)&Kc[off[kb][kt]];

    f32x16 st0[2], st1[2];
    __builtin_amdgcn_s_setprio(1);
#pragma unroll
    for (int kb = 0; kb < 2; ++kb) {
      f32x16 a = {};
#pragma unroll
      for (int kt = 0; kt < 4; ++kt)
        a = __builtin_amdgcn_mfma_f32_32x32x16_bf16(kf[kb][kt], qf0[kt], a, 0, 0, 0);
      st0[kb] = a;
    }
#pragma unroll
    for (int kb = 0; kb < 2; ++kb) {
      f32x16 a = {};
#pragma unroll
      for (int kt = 0; kt < 4; ++kt)
        a = __builtin_amdgcn_mfma_f32_32x32x16_bf16(kf[kb][kt], qf1[kt], a, 0, 0, 0);
      st1[kb] = a;
    }
    __builtin_amdgcn_s_setprio(0);

    unsigned pk0[16], pk1[16];
    {
      float s0 = 0.f, s1 = 0.f, s2 = 0.f, s3 = 0.f;
#pragma unroll
      for (int kb = 0; kb < 2; ++kb)
#pragma unroll
        for (int j = 0; j < 8; ++j) {
          float pa = __builtin_amdgcn_exp2f(st0[kb][2 * j]);
          float pb = __builtin_amdgcn_exp2f(st0[kb][2 * j + 1]);
          if ((j & 3) == 0) s0 += pa + pb;
          else if ((j & 3) == 1) s1 += pa + pb;
          else if ((j & 3) == 2) s2 += pa + pb;
          else s3 += pa + pb;
          pk0[kb * 8 + j] = cvtpk(pa, pb);
        }
      l0 += (s0 + s1) + (s2 + s3);
    }
    {
      float s0 = 0.f, s1 = 0.f, s2 = 0.f, s3 = 0.f;
#pragma unroll
      for (int kb = 0; kb < 2; ++kb)
#pragma unroll
        for (int j = 0; j < 8; ++j) {
          float pa = __builtin_amdgcn_exp2f(st1[kb][2 * j]);
          float pb = __builtin_amdgcn_exp2f(st1[kb][2 * j + 1]);
          if ((j & 3) == 0) s0 += pa + pb;
          else if ((j & 3) == 1) s1 += pa + pb;
          else if ((j & 3) == 2) s2 += pa + pb;
          else s3 += pa + pb;
          pk1[kb * 8 + j] = cvtpk(pa, pb);
        }
      l1 += (s0 + s1) + (s2 + s3);
    }

    bf16x8 pfrag0[4], pfrag1[4];
#pragma unroll
    for (int kt = 0; kt < 4; ++kt) {
      u32x2 sa = plswap(pk0[4 * kt + 0], pk0[4 * kt + 2]);
      u32x2 sb = plswap(pk0[4 * kt + 1], pk0[4 * kt + 3]);
      union { u32x4 u; bf16x8 b; } w;
      w.u.x = sa.x; w.u.y = sb.x; w.u.z = sa.y; w.u.w = sb.y;
      pfrag0[kt] = w.b;
      u32x2 sc = plswap(pk1[4 * kt + 0], pk1[4 * kt + 2]);
      u32x2 sd = plswap(pk1[4 * kt + 1], pk1[4 * kt + 3]);
      union { u32x4 u; bf16x8 b; } w2;
      w2.u.x = sc.x; w2.u.y = sd.x; w2.u.z = sc.y; w2.u.w = sd.y;
      pfrag1[kt] = w2.b;
    }

    __builtin_amdgcn_s_setprio(1);
#pragma unroll
    for (int dv = 0; dv < 2; ++dv) {
      bf16x8 vf[4];
#pragma unroll
      for (int kt = 0; kt < 4; ++kt)
        vf[kt] = *(const bf16x8*)&Vc[off[dv][kt]];
#pragma unroll
      for (int kt = 0; kt < 4; ++kt)
        oa0[dv] = __builtin_amdgcn_mfma_f32_32x32x16_bf16(vf[kt], pfrag0[kt], oa0[dv], 0, 0, 0);
#pragma unroll
      for (int kt = 0; kt < 4; ++kt)
        oa1[dv] = __builtin_amdgcn_mfma_f32_32x32x16_bf16(vf[kt], pfrag1[kt], oa1[dv], 0, 0, 0);
    }
    __builtin_amdgcn_s_setprio(0);

    if (t < 63) {
      writeKV(cur ^ 1);
      __syncthreads();
    }
  }

  const float inv0 = 1.0f / pair_sum(l0);
  const float inv1 = 1.0f / pair_sum(l1);
  const int qr0 = q0 + wid * 64 + l31;
#pragma unroll
  for (int dv = 0; dv < 2; ++dv)
#pragma unroll
    for (int tq = 0; tq < 4; ++tq) {
      int dh = 32 * dv + 8 * tq + 4 * hi;
      unsigned a0 = cvtpk(oa0[dv][4 * tq + 0] * inv0, oa0[dv][4 * tq + 1] * inv0);
      unsigned a1 = cvtpk(oa0[dv][4 * tq + 2] * inv0, oa0[dv][4 * tq + 3] * inv0);
      u32x2 wa = {a0, a1};
      *(u32x2*)&O[(size_t)qr0 * 2048 + h * 64 + dh] = wa;
      unsigned b0 = cvtpk(oa1[dv][4 * tq + 0] * inv1, oa1[dv][4 * tq + 1] * inv1);
      unsigned b1 = cvtpk(oa1[dv][4 * tq + 2] * inv1, oa1[dv][4 * tq + 3] * inv1);
      u32x2 wb = {b0, b1};
      *(u32x2*)&O[(size_t)(qr0 + 32) * 2048 + h * 64 + dh] = wb;
    }
}

// ---------- launch ----------
extern "C" void kernel_launch(void* const* d_in, const int* in_sizes, int n_in,
                              void* d_out, int out_size, void* d_ws, size_t ws_size,
                              hipStream_t stream) {
  const float* x  = (const float*)d_in[0];
  const float* Wq = (const float*)d_in[1];
  const float* bq = (const float*)d_in[2];
  const float* Wk = (const float*)d_in[3];
  const float* bk = (const float*)d_in[4];
  const float* Wv = (const float*)d_in[5];
  const float* bv = (const float*)d_in[6];
  const float* qn = (const float*)d_in[7];
  const float* kn = (const float*)d_in[8];
  const float* Wo = (const float*)d_in[9];
  const float* bo = (const float*)d_in[10];

  char* w = (char*)d_ws;
  unsigned short* Xbf = (unsigned short*)(w);                 // reused for O
  unsigned short* Wqb = (unsigned short*)(w + 16777216);
  unsigned short* Wkb = (unsigned short*)(w + 25165824);
  unsigned short* Wvb = (unsigned short*)(w + 33554432);
  unsigned short* Wob = (unsigned short*)(w + 41943040);
  unsigned short* Qb  = (unsigned short*)(w + 50331648);
  unsigned short* Kb  = (unsigned short*)(w + 67108864);
  unsigned short* Vb  = (unsigned short*)(w + 83886080);
  unsigned short* Ob  = Xbf;

  cast_all_kernel<<<3072, 256, 0, stream>>>(x, Wq, Wk, Wv, Wo,
                                            Xbf, Wqb, Wkb, Wvb, Wob);

  gemm256<0><<<dim3(48, 16), 512, 0, stream>>>(
      Xbf, Wqb, Wkb, Wvb, bq, bk, bv, Qb, Kb, Vb);

  rmsnorm2_kernel<<<8192, 256, 0, stream>>>(Qb, Kb, qn, kn);

  flash_attn<<<512, 256, 0, stream>>>(Qb, Kb, Vb, Ob);

  gemm256<1><<<dim3(16, 16), 512, 0, stream>>>(
      Ob, Wob, Wob, Wob, bo, bo, bo, d_out, d_out, d_out);
}